// Round 1
// baseline (245.552 us; speedup 1.0000x reference)
//
#include <hip/hip_runtime.h>
#include <stdint.h>

typedef _Float16 f16;
typedef _Float16 f16x8 __attribute__((ext_vector_type(8)));
typedef _Float16 f16x4 __attribute__((ext_vector_type(4)));
typedef float    f32x4 __attribute__((ext_vector_type(4)));

#define MFMA_F16(A, B, C) __builtin_amdgcn_mfma_f32_16x16x32_f16((A), (B), (C), 0, 0, 0)

__device__ __forceinline__ void gload_lds16(const void* g, void* l) {
  __builtin_amdgcn_global_load_lds((const __attribute__((address_space(1))) void*)g,
                                   (__attribute__((address_space(3))) void*)l, 16, 0, 0);
}

// ---------------------------------------------------------------- f32 -> f16 converts
// y=0: src (4M), y=1: tgt (4M), y=2: qw, y=3: kw, y=4: vw, y=5: ow (1M each)
__global__ void cvt_f32_f16(const float* __restrict__ s0, const float* __restrict__ s1,
                            const float* __restrict__ s2, const float* __restrict__ s3,
                            const float* __restrict__ s4, const float* __restrict__ s5,
                            f16* __restrict__ d0, f16* __restrict__ d1, f16* __restrict__ d2,
                            f16* __restrict__ d3, f16* __restrict__ d4, f16* __restrict__ d5) {
  const float* sp; f16* dp; int n4;
  switch (blockIdx.y) {
    case 0:  sp = s0; dp = d0; n4 = (4096 * 1024) / 4; break;
    case 1:  sp = s1; dp = d1; n4 = (4096 * 1024) / 4; break;
    case 2:  sp = s2; dp = d2; n4 = (1024 * 1024) / 4; break;
    case 3:  sp = s3; dp = d3; n4 = (1024 * 1024) / 4; break;
    case 4:  sp = s4; dp = d4; n4 = (1024 * 1024) / 4; break;
    default: sp = s5; dp = d5; n4 = (1024 * 1024) / 4; break;
  }
  int stride = gridDim.x * blockDim.x;
  for (int i = blockIdx.x * blockDim.x + threadIdx.x; i < n4; i += stride) {
    f32x4 v = *(const f32x4*)(sp + (size_t)i * 4);
    f16x4 h;
    h[0] = (f16)v[0]; h[1] = (f16)v[1]; h[2] = (f16)v[2]; h[3] = (f16)v[3];
    *(f16x4*)(dp + (size_t)i * 4) = h;
  }
}

// ---------------------------------------------------------------- GEMM core (K=N=1024, C = A * W^T)
// 128x128 tile, BK=32, 4 waves in 2x2, each wave 64x64 (4x4 frags of 16x16x32 f16 MFMA).
// Staging: global_load_lds dwordx4, linear LDS dest; XOR swizzle done by pre-swizzling the
// global source column so that reads (logical slot g, phys = g ^ ((row>>1)&3)) are ~conflict-free.
__device__ __forceinline__ void gemm_core_k1024(const f16* __restrict__ A, const f16* __restrict__ W,
                                                f16* lA, f16* lB, f32x4 (&acc)[4][4],
                                                int row0, int col0) {
  const int tid = threadIdx.x;
  const int lane = tid & 63;
  const int w = tid >> 6;
  const int g = lane >> 4, c = lane & 15;
  const int wr = (w >> 1) * 64, wc = (w & 1) * 64;

  int sr[2], scol[2];
#pragma unroll
  for (int p = 0; p < 2; ++p) {
    int slot = p * 256 + tid;
    int r = slot >> 2, sph = slot & 3;
    sr[p] = r;
    scol[p] = (sph ^ ((r >> 1) & 3)) * 8;
  }
  const f16* Abase = A + (size_t)row0 * 1024;
  const f16* Wbase = W + (size_t)col0 * 1024;

  for (int k0 = 0; k0 < 1024; k0 += 32) {
    __syncthreads();
#pragma unroll
    for (int p = 0; p < 2; ++p) {
      gload_lds16(Abase + (size_t)sr[p] * 1024 + k0 + scol[p], lA + (p * 256 + w * 64) * 8);
      gload_lds16(Wbase + (size_t)sr[p] * 1024 + k0 + scol[p], lB + (p * 256 + w * 64) * 8);
    }
    __syncthreads();
    f16x8 af[4], bf[4];
#pragma unroll
    for (int m = 0; m < 4; ++m) {
      int r = wr + m * 16 + c;
      af[m] = *(const f16x8*)(lA + r * 32 + (g ^ ((r >> 1) & 3)) * 8);
    }
#pragma unroll
    for (int n = 0; n < 4; ++n) {
      int r = wc + n * 16 + c;
      bf[n] = *(const f16x8*)(lB + r * 32 + (g ^ ((r >> 1) & 3)) * 8);
    }
#pragma unroll
    for (int m = 0; m < 4; ++m)
#pragma unroll
      for (int n = 0; n < 4; ++n)
        acc[m][n] = MFMA_F16(af[m], bf[n], acc[m][n]);
  }
}

// ---------------------------------------------------------------- fused projections
// z=0: q = src@qw^T (+qb) -> q16 [4096,1024]
// z=1: k = tgt@kw^T (+kb) -> k16 [4096,1024]
// z=2: v_src = src@vw^T (+vb) -> vtS transposed [(b*16+h)*64+d][1024]
// z=3: v_tgt = tgt@vw^T (+vb) -> vtT transposed
__global__ __launch_bounds__(256, 2) void proj_gemm(
    const f16* __restrict__ src16, const f16* __restrict__ tgt16,
    const f16* __restrict__ qw16, const f16* __restrict__ kw16, const f16* __restrict__ vw16,
    const float* __restrict__ qb, const float* __restrict__ kb, const float* __restrict__ vb,
    f16* __restrict__ q16, f16* __restrict__ k16, f16* __restrict__ vtS, f16* __restrict__ vtT) {
  __shared__ f16 lA[128 * 32];
  __shared__ f16 lB[128 * 32];
  const int z = blockIdx.z;
  const f16* A = (z & 1) ? tgt16 : src16;
  const f16* W = (z == 0) ? qw16 : (z == 1) ? kw16 : vw16;
  const float* bias = (z == 0) ? qb : (z == 1) ? kb : vb;
  const int row0 = blockIdx.y * 128;
  const int col0 = blockIdx.x * 128;
  f32x4 acc[4][4] = {};
  gemm_core_k1024(A, W, lA, lB, acc, row0, col0);

  const int lane = threadIdx.x & 63;
  const int w = threadIdx.x >> 6;
  const int g = lane >> 4, c = lane & 15;
  const int wr = (w >> 1) * 64, wc = (w & 1) * 64;

  if (z < 2) {
    f16* O = (z == 0) ? q16 : k16;
#pragma unroll
    for (int n = 0; n < 4; ++n) {
      int colg = col0 + wc + n * 16 + c;
      float bv = bias[colg];
#pragma unroll
      for (int m = 0; m < 4; ++m) {
        int rb = row0 + wr + m * 16 + g * 4;
#pragma unroll
        for (int r = 0; r < 4; ++r)
          O[(size_t)(rb + r) * 1024 + colg] = (f16)(acc[m][n][r] + bv);
      }
    }
  } else {
    f16* O = (z == 2) ? vtS : vtT;
#pragma unroll
    for (int n = 0; n < 4; ++n) {
      int colg = col0 + wc + n * 16 + c;   // = h*64 + d
      float bv = bias[colg];
#pragma unroll
      for (int m = 0; m < 4; ++m) {
        int row = row0 + wr + m * 16 + g * 4;   // token row (b*1024 + t)
        int bb = row >> 10, t = row & 1023;
        f16x4 pk;
#pragma unroll
        for (int r = 0; r < 4; ++r) pk[r] = (f16)(acc[m][n][r] + bv);
        *(f16x4*)(O + ((size_t)(bb << 10) + colg) * 1024 + t) = pk;  // 8B store, t%4==0
      }
    }
  }
}

// ---------------------------------------------------------------- output projection (f32 out)
__global__ __launch_bounds__(256, 2) void out_gemm(
    const f16* __restrict__ opre, const f16* __restrict__ ow16,
    const float* __restrict__ ob, float* __restrict__ out) {
  __shared__ f16 lA[128 * 32];
  __shared__ f16 lB[128 * 32];
  const int row0 = blockIdx.y * 128;
  const int col0 = blockIdx.x * 128;
  f32x4 acc[4][4] = {};
  gemm_core_k1024(opre, ow16, lA, lB, acc, row0, col0);
  const int lane = threadIdx.x & 63;
  const int w = threadIdx.x >> 6;
  const int g = lane >> 4, c = lane & 15;
  const int wr = (w >> 1) * 64, wc = (w & 1) * 64;
#pragma unroll
  for (int n = 0; n < 4; ++n) {
    int colg = col0 + wc + n * 16 + c;
    float bv = ob[colg];
#pragma unroll
    for (int m = 0; m < 4; ++m) {
      int rb = row0 + wr + m * 16 + g * 4;
#pragma unroll
      for (int r = 0; r < 4; ++r)
        out[(size_t)(rb + r) * 1024 + colg] = acc[m][n][r] + bv;
    }
  }
}

// ---------------------------------------------------------------- fused 2-pass flash attention
// pass 0: Q=q16, K=k16, V=vtT, mask=src_mask -> opre rows [0,4096)
// pass 1: Q=k16, K=q16, V=vtS, mask=tgt_mask -> opre rows [4096,8192)
// Block: 4 waves x 32 q-rows = 128 q-rows; KV tile = 64. K/V read from L2 (no staging).
// Per-row-uniform masking: score = raw*0.125*mask (masked rows -> uniform softmax, exact).
__global__ __launch_bounds__(256, 2) void attn_fwd(
    const f16* __restrict__ q16, const f16* __restrict__ k16,
    const f16* __restrict__ vtS, const f16* __restrict__ vtT,
    const int* __restrict__ smask, const int* __restrict__ tmask,
    f16* __restrict__ opre) {
  const int pass = blockIdx.z;
  const f16* Q  = pass ? k16 : q16;
  const f16* Kt = pass ? q16 : k16;
  const f16* VT = pass ? vtS : vtT;
  const int* qmask = pass ? tmask : smask;
  const int outRowOff = pass ? 4096 : 0;

  const int tid = threadIdx.x;
  const int lane = tid & 63, wv = tid >> 6;
  const int g = lane >> 4, c = lane & 15;
  const int bh = blockIdx.y, b = bh >> 4, h = bh & 15;
  const int qrow0 = blockIdx.x * 128 + wv * 32;

  __shared__ f16 Plds[4][32 * 72];   // per-wave P[q][t] tile, pitch 72 (16B-aligned, conflict-free)
  f16* myP = Plds[wv];

  const size_t qgbase = ((size_t)(b * 1024 + qrow0)) * 1024 + h * 64;
  f16x8 qf[2][2];
#pragma unroll
  for (int m = 0; m < 2; ++m)
#pragma unroll
    for (int kc = 0; kc < 2; ++kc)
      qf[m][kc] = *(const f16x8*)(Q + qgbase + (size_t)(m * 16 + c) * 1024 + kc * 32 + g * 8);

  float mqv[2][4];
#pragma unroll
  for (int m = 0; m < 2; ++m)
#pragma unroll
    for (int r = 0; r < 4; ++r)
      mqv[m][r] = (qmask[b * 1024 + qrow0 + m * 16 + g * 4 + r] != 0) ? 1.0f : 0.0f;

  f32x4 accO[2][4] = {};
  float mrun[2][4], lrun[2][4];
#pragma unroll
  for (int m = 0; m < 2; ++m)
#pragma unroll
    for (int r = 0; r < 4; ++r) { mrun[m][r] = -1e30f; lrun[m][r] = 0.0f; }

  const size_t kbase = (size_t)b * 1024 * 1024 + h * 64;
  const size_t vbase = (size_t)bh * 64 * 1024;

  for (int t0 = 0; t0 < 1024; t0 += 64) {
    f16x8 kf[4][2];
#pragma unroll
    for (int n = 0; n < 4; ++n)
#pragma unroll
      for (int kc = 0; kc < 2; ++kc)
        kf[n][kc] = *(const f16x8*)(Kt + kbase + (size_t)(t0 + n * 16 + c) * 1024 + kc * 32 + g * 8);

    f32x4 sc[2][4];
#pragma unroll
    for (int m = 0; m < 2; ++m)
#pragma unroll
      for (int n = 0; n < 4; ++n) {
        f32x4 zz = {0.0f, 0.0f, 0.0f, 0.0f};
        zz = MFMA_F16(qf[m][0], kf[n][0], zz);
        sc[m][n] = MFMA_F16(qf[m][1], kf[n][1], zz);
      }

    // online softmax; C-frag rows: q-local = m*16 + g*4 + r, cols: t-local = n*16 + c
    float p[2][4][4];
#pragma unroll
    for (int m = 0; m < 2; ++m) {
#pragma unroll
      for (int r = 0; r < 4; ++r) {
        float msk = mqv[m][r];
        float v0 = sc[m][0][r] * 0.125f * msk;
        float v1 = sc[m][1][r] * 0.125f * msk;
        float v2 = sc[m][2][r] * 0.125f * msk;
        float v3 = sc[m][3][r] * 0.125f * msk;
        float mx = fmaxf(fmaxf(v0, v1), fmaxf(v2, v3));
        mx = fmaxf(mx, __shfl_xor(mx, 1));
        mx = fmaxf(mx, __shfl_xor(mx, 2));
        mx = fmaxf(mx, __shfl_xor(mx, 4));
        mx = fmaxf(mx, __shfl_xor(mx, 8));
        float mnew = fmaxf(mrun[m][r], mx);
        float alpha = __expf(mrun[m][r] - mnew);
        float e0 = __expf(v0 - mnew);
        float e1 = __expf(v1 - mnew);
        float e2 = __expf(v2 - mnew);
        float e3 = __expf(v3 - mnew);
        float sm = e0 + e1 + e2 + e3;
        sm += __shfl_xor(sm, 1);
        sm += __shfl_xor(sm, 2);
        sm += __shfl_xor(sm, 4);
        sm += __shfl_xor(sm, 8);
        lrun[m][r] = lrun[m][r] * alpha + sm;
        mrun[m][r] = mnew;
        p[m][0][r] = e0; p[m][1][r] = e1; p[m][2][r] = e2; p[m][3][r] = e3;
#pragma unroll
        for (int n = 0; n < 4; ++n) accO[m][n][r] *= alpha;
      }
    }

    // transpose P through per-wave LDS: write C-layout, read A-frag layout
#pragma unroll
    for (int m = 0; m < 2; ++m)
#pragma unroll
      for (int n = 0; n < 4; ++n)
#pragma unroll
        for (int r = 0; r < 4; ++r)
          myP[(m * 16 + g * 4 + r) * 72 + n * 16 + c] = (f16)p[m][n][r];
    asm volatile("s_waitcnt lgkmcnt(0)" ::: "memory");

    f16x8 pa[2][2];
#pragma unroll
    for (int m = 0; m < 2; ++m)
#pragma unroll
      for (int kc = 0; kc < 2; ++kc)
        pa[m][kc] = *(const f16x8*)(myP + (m * 16 + c) * 72 + kc * 32 + g * 8);
    asm volatile("" ::: "memory");  // keep next-iter P writes after these reads

    f16x8 vf[4][2];
#pragma unroll
    for (int n = 0; n < 4; ++n)
#pragma unroll
      for (int kc = 0; kc < 2; ++kc)
        vf[n][kc] = *(const f16x8*)(VT + vbase + (size_t)(n * 16 + c) * 1024 + t0 + kc * 32 + g * 8);
#pragma unroll
    for (int m = 0; m < 2; ++m)
#pragma unroll
      for (int n = 0; n < 4; ++n) {
        accO[m][n] = MFMA_F16(pa[m][0], vf[n][0], accO[m][n]);
        accO[m][n] = MFMA_F16(pa[m][1], vf[n][1], accO[m][n]);
      }
  }

#pragma unroll
  for (int m = 0; m < 2; ++m)
#pragma unroll
    for (int r = 0; r < 4; ++r) {
      float inv = 1.0f / lrun[m][r];
      size_t orow = (size_t)(outRowOff + b * 1024 + qrow0 + m * 16 + g * 4 + r);
#pragma unroll
      for (int n = 0; n < 4; ++n)
        opre[orow * 1024 + h * 64 + n * 16 + c] = (f16)(accO[m][n][r] * inv);
    }
}

// ---------------------------------------------------------------- launcher
extern "C" void kernel_launch(void* const* d_in, const int* in_sizes, int n_in,
                              void* d_out, int out_size, void* d_ws, size_t ws_size,
                              hipStream_t stream) {
  (void)in_sizes; (void)n_in; (void)out_size; (void)ws_size;
  const float* src = (const float*)d_in[0];
  const float* tgt = (const float*)d_in[1];
  const int*   smask = (const int*)d_in[2];
  const int*   tmask = (const int*)d_in[3];
  const float* qw = (const float*)d_in[4];
  const float* qb = (const float*)d_in[5];
  const float* kw = (const float*)d_in[6];
  const float* kb = (const float*)d_in[7];
  const float* vw = (const float*)d_in[8];
  const float* vb = (const float*)d_in[9];
  const float* ow = (const float*)d_in[10];
  const float* ob = (const float*)d_in[11];
  float* out = (float*)d_out;

  f16* wsp = (f16*)d_ws;
  const size_t M4 = (size_t)4096 * 1024;
  const size_t M1 = (size_t)1024 * 1024;
  f16* src16 = wsp;                 // [0, 4M)
  f16* tgt16 = src16 + M4;          // [4M, 8M)
  f16* qw16  = tgt16 + M4;          // 8M
  f16* kw16  = qw16 + M1;           // 9M
  f16* vw16  = kw16 + M1;           // 10M
  f16* ow16  = vw16 + M1;           // 11M
  f16* q16   = ow16 + M1;           // 12M
  f16* k16   = q16 + M4;            // 16M
  f16* vtS   = k16 + M4;            // 20M
  f16* vtT   = vtS + M4;            // 24M..28M  (total 56MB)
  f16* opre  = wsp;                 // reuses src16+tgt16 region (8M f16), dead by attention time

  cvt_f32_f16<<<dim3(512, 6), 256, 0, stream>>>(src, tgt, qw, kw, vw, ow,
                                                src16, tgt16, qw16, kw16, vw16, ow16);
  proj_gemm<<<dim3(8, 32, 4), 256, 0, stream>>>(src16, tgt16, qw16, kw16, vw16,
                                                qb, kb, vb, q16, k16, vtS, vtT);
  attn_fwd<<<dim3(8, 64, 2), 256, 0, stream>>>(q16, k16, vtS, vtT, smask, tmask, opre);
  out_gemm<<<dim3(8, 64), 256, 0, stream>>>(opre, ow16, ob, out);
}